// Round 3
// baseline (368.892 us; speedup 1.0000x reference)
//
#include <hip/hip_runtime.h>
#include <cstdint>

typedef short short8 __attribute__((ext_vector_type(8)));
typedef float f32x4 __attribute__((ext_vector_type(4)));

#define LDS_AS3(p) ((__attribute__((address_space(3))) unsigned*)(p))
#define GLB_AS1(p) ((const __attribute__((address_space(1))) unsigned*)(p))

// fp32 -> bf16 (round-to-nearest-even), two packed into a u32
__device__ inline unsigned bfpack(float a, float b) {
    union { float f; unsigned u; } ua, ub;
    ua.f = a; ub.f = b;
    unsigned lo = (ua.u + 0x7FFFu + ((ua.u >> 16) & 1u)) >> 16;
    unsigned hi = (ub.u + 0x7FFFu + ((ub.u >> 16) & 1u)) & 0xFFFF0000u;
    return lo | hi;
}

// ------------- prepass: convert + transpose W[512][N] -> WT[N][512] bf16 ----
template <int N>
__global__ __launch_bounds__(256)
void cvt_w(const float* __restrict__ W, unsigned short* __restrict__ WT)
{
    const int g = blockIdx.x * 256 + threadIdx.x;
    if (g >= N * 64) return;
    const int n = g % N, d8 = g / N;           // consecutive lanes -> consecutive n
    const float* p = W + (size_t)d8 * 8 * N + n;
    uint4 u;
    u.x = bfpack(p[0],             p[(size_t)N]);
    u.y = bfpack(p[2 * (size_t)N], p[3 * (size_t)N]);
    u.z = bfpack(p[4 * (size_t)N], p[5 * (size_t)N]);
    u.w = bfpack(p[6 * (size_t)N], p[7 * (size_t)N]);
    *(uint4*)(WT + (size_t)n * 512 + d8 * 8) = u;
}

// ---------------- GEMM ( [B*K_L x 512] @ [512 x N] ) + closed-form scatter --
// A: fp32 X loaded to regs early, cvt+ds_write late (swizzled dest).
// B: bf16 WT via global_load_lds(16B), swizzle on global source (rule #21).
// 2-phase double-buffered K-loop; XCD-chunked bijective block swizzle.
template <int MODE>
__global__ __launch_bounds__(256)
void gemm_scatter(const float* __restrict__ X,
                  const unsigned short* __restrict__ WT,
                  const float* __restrict__ BIAS, float* __restrict__ Y)
{
    constexpr int K_L  = (MODE == 0) ? 64 : (MODE == 1) ? 128 : 256;
    constexpr int LOGK = (MODE == 0) ? 6  : (MODE == 1) ? 7   : 8;
    constexpr int N    = (MODE == 0) ? 1180 : (MODE == 1) ? 2881 : 1153;
    constexpr int XOFF = (MODE == 0) ? 0 : (MODE == 1) ? 64 : 192;
    constexpr int NT   = (N + 127) / 128;

    __shared__ __align__(16) unsigned short lA[2][128 * 32];
    __shared__ __align__(16) unsigned short lB[2][128 * 32];

    const int t    = threadIdx.x;
    const int lane = t & 63;
    const int wave = t >> 6;
    const int wr   = wave >> 1, wc = wave & 1;

    // bijective XCD-chunk swizzle (all grids divisible by 8); N-minor order
    const int cpx = (int)gridDim.x >> 3;
    const int wg  = (blockIdx.x & 7) * cpx + (blockIdx.x >> 3);
    const int nt  = wg % NT;
    const int mt  = wg / NT;
    const int m0  = mt * 128;
    const int n0  = nt * 128;

    f32x4 acc[4][4] = {};
    float4 av[2][2];                       // in-flight A tile (fp32)

    // ---- staging helpers -------------------------------------------------
    auto loadA = [&](int kk) {             // global -> regs (issue early)
        #pragma unroll
        for (int i = 0; i < 2; ++i) {
            const int cidx = i * 256 + t;  // 512 slots: row=cidx>>2, kg=cidx&3
            const int row  = cidx >> 2;
            const int kg   = cidx & 3;
            const int m    = m0 + row;
            const int b    = m >> LOGK;
            const int kd   = m & (K_L - 1);
            const float* p = X + ((size_t)(b * 448 + XOFF + kd) << 9) + kk + kg * 8;
            av[i][0] = *(const float4*)p;
            av[i][1] = *(const float4*)(p + 4);
        }
    };
    auto writeA = [&](int buf) {           // cvt + ds_write (swizzled dest)
        #pragma unroll
        for (int i = 0; i < 2; ++i) {
            const int cidx = i * 256 + t;
            const int row  = cidx >> 2;
            const int slot = (cidx & 3) ^ ((row >> 1) & 3);
            uint4 u;
            u.x = bfpack(av[i][0].x, av[i][0].y);
            u.y = bfpack(av[i][0].z, av[i][0].w);
            u.z = bfpack(av[i][1].x, av[i][1].y);
            u.w = bfpack(av[i][1].z, av[i][1].w);
            *(uint4*)(&lA[buf][(row * 4 + slot) * 8]) = u;
        }
    };
    auto stageB = [&](int buf, int kk) {   // gload_lds, pre-swizzled source
        #pragma unroll
        for (int i = 0; i < 2; ++i) {
            const int cidx = i * 256 + t;
            const int row  = cidx >> 2;
            const int kgl  = (cidx & 3) ^ ((row >> 1) & 3);
            int gc = n0 + row; if (gc > N - 1) gc = N - 1;   // N-tail clamp
            const unsigned short* gp = WT + (size_t)gc * 512 + kk + kgl * 8;
            __builtin_amdgcn_global_load_lds(GLB_AS1(gp), LDS_AS3(&lB[buf][cidx * 8]), 16, 0, 0);
        }
    };

    // ---- prologue --------------------------------------------------------
    loadA(0);
    stageB(0, 0);
    writeA(0);
    __syncthreads();

    // ---- 2-phase pipelined K-loop (16 steps of BK=32) --------------------
    int cur = 0;
    #pragma unroll 1
    for (int ks = 0; ks < 16; ++ks) {
        const int nxt = cur ^ 1;
        if (ks < 15) {                      // issue next-tile loads first
            loadA((ks + 1) * 32);
            stageB(nxt, (ks + 1) * 32);
        }
        const int kgl  = lane >> 4;
        const int lr16 = lane & 15;
        short8 af[4], bfr[4];
        #pragma unroll
        for (int mi = 0; mi < 4; ++mi) {
            const int row = wr * 64 + mi * 16 + lr16;
            af[mi] = *(const short8*)(&lA[cur][(row * 4 + (kgl ^ ((row >> 1) & 3))) * 8]);
        }
        #pragma unroll
        for (int ni = 0; ni < 4; ++ni) {
            const int row = wc * 64 + ni * 16 + lr16;
            bfr[ni] = *(const short8*)(&lB[cur][(row * 4 + (kgl ^ ((row >> 1) & 3))) * 8]);
        }
        #pragma unroll
        for (int mi = 0; mi < 4; ++mi)
            #pragma unroll
            for (int ni = 0; ni < 4; ++ni)
                acc[mi][ni] = __builtin_amdgcn_mfma_f32_16x16x32_bf16(
                    af[mi], bfr[ni], acc[mi][ni], 0, 0, 0);
        if (ks < 15) {
            writeA(nxt);                    // cvt + LDS write after MFMA
            __syncthreads();                // drains vmcnt (gload_lds) + lgkm
        }
        cur = nxt;
    }

    // ---- epilogue: bias add + closed-form scatter (verified R0/R1) -------
    const int lr = lane & 15;
    const int lq = lane >> 4;
    #pragma unroll
    for (int ni = 0; ni < 4; ++ni) {
        const int n = n0 + wc * 64 + ni * 16 + lr;
        if (n >= N) continue;
        const float bias = BIAS[n];
        #pragma unroll
        for (int mi = 0; mi < 4; ++mi) {
            #pragma unroll
            for (int r = 0; r < 4; ++r) {
                const int m  = m0 + wr * 64 + mi * 16 + lq * 4 + r;
                const int b  = m >> LOGK;
                const int kd = m & (K_L - 1);
                const float v = acc[mi][ni][r] + bias;
                float* yb = Y + (size_t)b * 370816;
                if (MODE == 0) {
                    if (n < 27)       yb[kd * 27 + n] = v;
                    else if (n == 27) yb[1728 + kd]   = v;
                    else {
                        int tt = n - 28, kn = tt / 9, j = tt - kn * 9;
                        yb[1792 + kn * 576 + kd * 9 + j] = 0.5f * v;
                    }
                } else if (MODE == 1) {
                    if (n < 576)       yb[1792 + kd * 576 + n] += 0.5f * v;
                    else if (n == 576) yb[75520 + kd] = 0.5f * v;
                    else {
                        int tt = n - 577, kn = tt / 9, j = tt - kn * 9;
                        yb[75648 + kn * 1152 + kd * 9 + j] = v;
                    }
                } else {
                    if (n < 1152) yb[75648 + kd * 1152 + n] += v;
                    else          yb[370560 + kd] = v;
                }
            }
        }
    }
}

extern "C" void kernel_launch(void* const* d_in, const int* in_sizes, int n_in,
                              void* d_out, int out_size, void* d_ws, size_t ws_size,
                              hipStream_t stream)
{
    const float* x  = (const float*)d_in[0];
    const float* W0 = (const float*)d_in[1];
    const float* b0 = (const float*)d_in[2];
    const float* W1 = (const float*)d_in[3];
    const float* b1 = (const float*)d_in[4];
    const float* W2 = (const float*)d_in[5];
    const float* b2 = (const float*)d_in[6];
    float* y = (float*)d_out;

    // ws layout (bf16): WT0[1180*512] | WT1[2881*512] | WT2[1153*512]  (5.3 MB)
    unsigned short* WT0 = (unsigned short*)d_ws;
    unsigned short* WT1 = WT0 + (size_t)1180 * 512;
    unsigned short* WT2 = WT1 + (size_t)2881 * 512;
    const size_t NEED = (size_t)(1180 + 2881 + 1153) * 512 * 2;
    if (ws_size < NEED) return;   // ws established >= 61 MB in R1; cannot trigger

    cvt_w<1180><<<dim3((1180 * 64 + 255) / 256), 256, 0, stream>>>(W0, WT0);
    cvt_w<2881><<<dim3((2881 * 64 + 255) / 256), 256, 0, stream>>>(W1, WT1);
    cvt_w<1153><<<dim3((1153 * 64 + 255) / 256), 256, 0, stream>>>(W2, WT2);

    // grids: (M/128) * ceil(N/128); stream order carries the += dependency
    gemm_scatter<0><<<dim3(64 * 10),  256, 0, stream>>>(x, WT0, b0, y);
    gemm_scatter<1><<<dim3(128 * 23), 256, 0, stream>>>(x, WT1, b1, y);
    gemm_scatter<2><<<dim3(256 * 10), 256, 0, stream>>>(x, WT2, b2, y);
}

// Round 4
// 308.159 us; speedup vs baseline: 1.1971x; 1.1971x over previous
//
#include <hip/hip_runtime.h>
#include <cstdint>

typedef short short8 __attribute__((ext_vector_type(8)));
typedef float f32x4 __attribute__((ext_vector_type(4)));

#define LDS_AS3(p) ((__attribute__((address_space(3))) unsigned*)(p))
#define GLB_AS1(p) ((const __attribute__((address_space(1))) unsigned*)(p))

// fp32 -> bf16 (round-to-nearest-even), two packed into a u32
__device__ inline unsigned bfpack(float a, float b) {
    union { float f; unsigned u; } ua, ub;
    ua.f = a; ub.f = b;
    unsigned lo = (ua.u + 0x7FFFu + ((ua.u >> 16) & 1u)) >> 16;
    unsigned hi = (ub.u + 0x7FFFu + ((ub.u >> 16) & 1u)) & 0xFFFF0000u;
    return lo | hi;
}

// ---------------- prepass: convert X to bf16 (same [.,448,512] layout) ------
__global__ __launch_bounds__(256)
void cvt_x(const float* __restrict__ X, unsigned short* __restrict__ XB)
{
    const int g = blockIdx.x * 256 + threadIdx.x;   // 8 elems per thread, exact
    const float4 v0 = *(const float4*)(X + (size_t)g * 8);
    const float4 v1 = *(const float4*)(X + (size_t)g * 8 + 4);
    uint4 u;
    u.x = bfpack(v0.x, v0.y); u.y = bfpack(v0.z, v0.w);
    u.z = bfpack(v1.x, v1.y); u.w = bfpack(v1.z, v1.w);
    *(uint4*)(XB + (size_t)g * 8) = u;
}

// ------------- prepass: convert + transpose W[512][N] -> WT[N][512] bf16 ----
template <int N>
__global__ __launch_bounds__(256)
void cvt_w(const float* __restrict__ W, unsigned short* __restrict__ WT)
{
    const int g = blockIdx.x * 256 + threadIdx.x;
    if (g >= N * 64) return;
    const int n = g % N, d8 = g / N;           // consecutive lanes -> consecutive n
    const float* p = W + (size_t)d8 * 8 * N + n;
    uint4 u;
    u.x = bfpack(p[0],             p[(size_t)N]);
    u.y = bfpack(p[2 * (size_t)N], p[3 * (size_t)N]);
    u.z = bfpack(p[4 * (size_t)N], p[5 * (size_t)N]);
    u.w = bfpack(p[6 * (size_t)N], p[7 * (size_t)N]);
    *(uint4*)(WT + (size_t)n * 512 + d8 * 8) = u;
}

// ---------------- GEMM ( [B*K_L x 512] @ [512 x N] ) + closed-form scatter --
// Both operands bf16 in ws; staged via global_load_lds(16B) with the swizzle
// applied on the GLOBAL source side (rule #21). 2-phase double-buffered
// K-loop: STAGE(next) issued before ds_read+MFMA(cur), ONE barrier per step.
template <int MODE>
__global__ __launch_bounds__(256)
void gemm_scatter(const unsigned short* __restrict__ XB,
                  const unsigned short* __restrict__ WT,
                  const float* __restrict__ BIAS, float* __restrict__ Y)
{
    constexpr int K_L  = (MODE == 0) ? 64 : (MODE == 1) ? 128 : 256;
    constexpr int LOGK = (MODE == 0) ? 6  : (MODE == 1) ? 7   : 8;
    constexpr int N    = (MODE == 0) ? 1180 : (MODE == 1) ? 2881 : 1153;
    constexpr int XOFF = (MODE == 0) ? 0 : (MODE == 1) ? 64 : 192;
    constexpr int NT   = (N + 127) / 128;

    __shared__ __align__(16) unsigned short lA[2][128 * 32];
    __shared__ __align__(16) unsigned short lB[2][128 * 32];

    const int t    = threadIdx.x;
    const int lane = t & 63;
    const int wave = t >> 6;
    const int wr   = wave >> 1, wc = wave & 1;

    // bijective XCD-chunk swizzle (all grids divisible by 8); N-minor order
    const int cpx = (int)gridDim.x >> 3;
    const int wg  = (blockIdx.x & 7) * cpx + (blockIdx.x >> 3);
    const int nt  = wg % NT;
    const int mt  = wg / NT;
    const int m0  = mt * 128;
    const int n0  = nt * 128;

    f32x4 acc[4][4] = {};

    auto stage = [&](int buf, int kk) {
        // A: 512 x 16B chunks, linear LDS dest, swizzled source k-group
        #pragma unroll
        for (int i = 0; i < 2; ++i) {
            const int cidx = i * 256 + t;
            const int row  = cidx >> 2;
            const int kgl  = (cidx & 3) ^ ((row >> 1) & 3);
            const int m    = m0 + row;
            const int b    = m >> LOGK;
            const int kd   = m & (K_L - 1);
            const unsigned short* gp =
                XB + ((size_t)(b * 448 + XOFF + kd) << 9) + kk + kgl * 8;
            __builtin_amdgcn_global_load_lds(GLB_AS1(gp), LDS_AS3(&lA[buf][cidx * 8]), 16, 0, 0);
        }
        // B from transposed bf16 W
        #pragma unroll
        for (int i = 0; i < 2; ++i) {
            const int cidx = i * 256 + t;
            const int row  = cidx >> 2;
            const int kgl  = (cidx & 3) ^ ((row >> 1) & 3);
            int gc = n0 + row; if (gc > N - 1) gc = N - 1;   // N-tail clamp
            const unsigned short* gp = WT + (size_t)gc * 512 + kk + kgl * 8;
            __builtin_amdgcn_global_load_lds(GLB_AS1(gp), LDS_AS3(&lB[buf][cidx * 8]), 16, 0, 0);
        }
    };

    // ---- prologue: stage tile 0, drain, enter loop -----------------------
    stage(0, 0);
    __syncthreads();

    // ---- 2-phase pipelined K-loop (16 steps of BK=32) --------------------
    int cur = 0;
    #pragma unroll 1
    for (int ks = 0; ks < 16; ++ks) {
        const int nxt = cur ^ 1;
        if (ks < 15) stage(nxt, (ks + 1) * 32);   // issue next-tile loads first

        const int kgl  = lane >> 4;
        const int lr16 = lane & 15;
        short8 af[4], bfr[4];
        #pragma unroll
        for (int mi = 0; mi < 4; ++mi) {
            const int row = wr * 64 + mi * 16 + lr16;
            af[mi] = *(const short8*)(&lA[cur][(row * 4 + (kgl ^ ((row >> 1) & 3))) * 8]);
        }
        #pragma unroll
        for (int ni = 0; ni < 4; ++ni) {
            const int row = wc * 64 + ni * 16 + lr16;
            bfr[ni] = *(const short8*)(&lB[cur][(row * 4 + (kgl ^ ((row >> 1) & 3))) * 8]);
        }
        #pragma unroll
        for (int mi = 0; mi < 4; ++mi)
            #pragma unroll
            for (int ni = 0; ni < 4; ++ni)
                acc[mi][ni] = __builtin_amdgcn_mfma_f32_16x16x32_bf16(
                    af[mi], bfr[ni], acc[mi][ni], 0, 0, 0);

        __syncthreads();   // drains vmcnt (stage) + lgkm; one barrier per step
        cur = nxt;
    }

    // ---- epilogue: bias add + closed-form scatter (verified R0/R1/R2) ----
    const int lr = lane & 15;
    const int lq = lane >> 4;
    #pragma unroll
    for (int ni = 0; ni < 4; ++ni) {
        const int n = n0 + wc * 64 + ni * 16 + lr;
        if (n >= N) continue;
        const float bias = BIAS[n];
        #pragma unroll
        for (int mi = 0; mi < 4; ++mi) {
            #pragma unroll
            for (int r = 0; r < 4; ++r) {
                const int m  = m0 + wr * 64 + mi * 16 + lq * 4 + r;
                const int b  = m >> LOGK;
                const int kd = m & (K_L - 1);
                const float v = acc[mi][ni][r] + bias;
                float* yb = Y + (size_t)b * 370816;
                if (MODE == 0) {
                    if (n < 27)       yb[kd * 27 + n] = v;
                    else if (n == 27) yb[1728 + kd]   = v;
                    else {
                        int tt = n - 28, kn = tt / 9, j = tt - kn * 9;
                        yb[1792 + kn * 576 + kd * 9 + j] = 0.5f * v;
                    }
                } else if (MODE == 1) {
                    if (n < 576)       yb[1792 + kd * 576 + n] += 0.5f * v;
                    else if (n == 576) yb[75520 + kd] = 0.5f * v;
                    else {
                        int tt = n - 577, kn = tt / 9, j = tt - kn * 9;
                        yb[75648 + kn * 1152 + kd * 9 + j] = v;
                    }
                } else {
                    if (n < 1152) yb[75648 + kd * 1152 + n] += v;
                    else          yb[370560 + kd] = v;
                }
            }
        }
    }
}

extern "C" void kernel_launch(void* const* d_in, const int* in_sizes, int n_in,
                              void* d_out, int out_size, void* d_ws, size_t ws_size,
                              hipStream_t stream)
{
    const float* x  = (const float*)d_in[0];
    const float* W0 = (const float*)d_in[1];
    const float* b0 = (const float*)d_in[2];
    const float* W1 = (const float*)d_in[3];
    const float* b1 = (const float*)d_in[4];
    const float* W2 = (const float*)d_in[5];
    const float* b2 = (const float*)d_in[6];
    float* y = (float*)d_out;

    // ws layout (bf16): XB[128*448*512] | WT0[1180*512] | WT1[2881*512] | WT2[1153*512]
    unsigned short* XB  = (unsigned short*)d_ws;
    unsigned short* WT0 = XB  + (size_t)128 * 448 * 512;
    unsigned short* WT1 = WT0 + (size_t)1180 * 512;
    unsigned short* WT2 = WT1 + (size_t)2881 * 512;

    cvt_x<<<dim3(14336), 256, 0, stream>>>(x, XB);     // 128*448*512 / 8 / 256
    cvt_w<1180><<<dim3((1180 * 64 + 255) / 256), 256, 0, stream>>>(W0, WT0);
    cvt_w<2881><<<dim3((2881 * 64 + 255) / 256), 256, 0, stream>>>(W1, WT1);
    cvt_w<1153><<<dim3((1153 * 64 + 255) / 256), 256, 0, stream>>>(W2, WT2);

    // grids: (M/128) * ceil(N/128); stream order carries the += dependency
    gemm_scatter<0><<<dim3(64 * 10),  256, 0, stream>>>(XB, WT0, b0, y);
    gemm_scatter<1><<<dim3(128 * 23), 256, 0, stream>>>(XB, WT1, b1, y);
    gemm_scatter<2><<<dim3(256 * 10), 256, 0, stream>>>(XB, WT2, b2, y);
}

// Round 5
// 302.184 us; speedup vs baseline: 1.2208x; 1.0198x over previous
//
#include <hip/hip_runtime.h>
#include <cstdint>

typedef short short8 __attribute__((ext_vector_type(8)));
typedef float f32x4 __attribute__((ext_vector_type(4)));

#define LDS_AS3(p) ((__attribute__((address_space(3))) unsigned*)(p))
#define GLB_AS1(p) ((const __attribute__((address_space(1))) unsigned*)(p))

// fp32 -> bf16 (round-to-nearest-even), two packed into a u32
__device__ inline unsigned bfpack(float a, float b) {
    union { float f; unsigned u; } ua, ub;
    ua.f = a; ub.f = b;
    unsigned lo = (ua.u + 0x7FFFu + ((ua.u >> 16) & 1u)) >> 16;
    unsigned hi = (ub.u + 0x7FFFu + ((ub.u >> 16) & 1u)) & 0xFFFF0000u;
    return lo | hi;
}
__device__ inline unsigned short bf16of(float a) { return (unsigned short)bfpack(a, 0.0f); }
__device__ inline float bf2f(unsigned short s) {
    union { unsigned u; float f; } x; x.u = (unsigned)s << 16; return x.f;
}

// ---------------- prepass: convert X to bf16 (same [.,448,512] layout) ------
__global__ __launch_bounds__(256)
void cvt_x(const float* __restrict__ X, unsigned short* __restrict__ XB)
{
    const int g = blockIdx.x * 256 + threadIdx.x;   // 8 elems/thread, exact
    const float4 v0 = *(const float4*)(X + (size_t)g * 8);
    const float4 v1 = *(const float4*)(X + (size_t)g * 8 + 4);
    uint4 u;
    u.x = bfpack(v0.x, v0.y); u.y = bfpack(v0.z, v0.w);
    u.z = bfpack(v1.x, v1.y); u.w = bfpack(v1.z, v1.w);
    *(uint4*)(XB + (size_t)g * 8) = u;
}

// ------------- prepass: convert + transpose W[512][N] -> WT[N][512] bf16 ----
template <int N>
__global__ __launch_bounds__(256)
void cvt_w(const float* __restrict__ W, unsigned short* __restrict__ WT)
{
    const int g = blockIdx.x * 256 + threadIdx.x;
    if (g >= N * 64) return;
    const int n = g % N, d8 = g / N;
    const float* p = W + (size_t)d8 * 8 * N + n;
    uint4 u;
    u.x = bfpack(p[0],             p[(size_t)N]);
    u.y = bfpack(p[2 * (size_t)N], p[3 * (size_t)N]);
    u.z = bfpack(p[4 * (size_t)N], p[5 * (size_t)N]);
    u.w = bfpack(p[6 * (size_t)N], p[7 * (size_t)N]);
    *(uint4*)(WT + (size_t)n * 512 + d8 * 8) = u;
}

// ---------------- GEMM ( [B*K_L x 512] @ [512 x N] ) + scatter --------------
// 3-deep pipeline: raw s_barrier + counted s_waitcnt vmcnt(4) (never 0 mid-
// loop); gload_lds(16B) staging, swizzle on global source (rule #21).
// FUSED: ext terms hand off via bf16 ws (Y written exactly once, no RMW).
template <int MODE, bool FUSED>
__global__ __launch_bounds__(256)
void gemm_scatter(const unsigned short* __restrict__ XB,
                  const unsigned short* __restrict__ WT,
                  const float* __restrict__ BIAS, float* __restrict__ Y,
                  const unsigned short* __restrict__ EXTI,   // prev layer's ext
                  unsigned short* __restrict__ EXTO)         // our ext out
{
    constexpr int K_L  = (MODE == 0) ? 64 : (MODE == 1) ? 128 : 256;
    constexpr int LOGK = (MODE == 0) ? 6  : (MODE == 1) ? 7   : 8;
    constexpr int N    = (MODE == 0) ? 1180 : (MODE == 1) ? 2881 : 1153;
    constexpr int XOFF = (MODE == 0) ? 0 : (MODE == 1) ? 64 : 192;
    constexpr int NT   = (N + 127) / 128;

    __shared__ __align__(16) unsigned short lA[3][128 * 32];
    __shared__ __align__(16) unsigned short lB[3][128 * 32];

    const int t    = threadIdx.x;
    const int lane = t & 63;
    const int wave = t >> 6;
    const int wr   = wave >> 1, wc = wave & 1;

    // bijective XCD-chunk swizzle (all grids divisible by 8); N-minor order
    const int cpx = (int)gridDim.x >> 3;
    const int wg  = (blockIdx.x & 7) * cpx + (blockIdx.x >> 3);
    const int nt  = wg % NT;
    const int mt  = wg / NT;
    const int m0  = mt * 128;
    const int n0  = nt * 128;

    f32x4 acc[4][4] = {};

    auto stage = [&](int buf, int kk) {
        #pragma unroll
        for (int i = 0; i < 2; ++i) {
            const int cidx = i * 256 + t;
            const int row  = cidx >> 2;
            const int kgl  = (cidx & 3) ^ ((row >> 1) & 3);
            const int m    = m0 + row;
            const int b    = m >> LOGK;
            const int kd   = m & (K_L - 1);
            const unsigned short* gp =
                XB + ((size_t)(b * 448 + XOFF + kd) << 9) + kk + kgl * 8;
            __builtin_amdgcn_global_load_lds(GLB_AS1(gp), LDS_AS3(&lA[buf][cidx * 8]), 16, 0, 0);
        }
        #pragma unroll
        for (int i = 0; i < 2; ++i) {
            const int cidx = i * 256 + t;
            const int row  = cidx >> 2;
            const int kgl  = (cidx & 3) ^ ((row >> 1) & 3);
            int gc = n0 + row; if (gc > N - 1) gc = N - 1;   // N-tail clamp
            const unsigned short* gp = WT + (size_t)gc * 512 + kk + kgl * 8;
            __builtin_amdgcn_global_load_lds(GLB_AS1(gp), LDS_AS3(&lB[buf][cidx * 8]), 16, 0, 0);
        }
    };

    // ---- prologue: two tiles in flight -----------------------------------
    stage(0, 0);
    stage(1, 32);

    // ---- 3-deep pipelined K-loop (16 steps of BK=32) ---------------------
    int cur = 0;
    #pragma unroll 1
    for (int ks = 0; ks < 16; ++ks) {
        // retire exactly tile ks (<=2 newer stages, 4 instr each, in flight)
        if (ks == 15) asm volatile("s_waitcnt vmcnt(0)" ::: "memory");
        else          asm volatile("s_waitcnt vmcnt(4)" ::: "memory");
        __builtin_amdgcn_s_barrier();   // raw: no vmcnt drain (T4)

        const int kgl  = lane >> 4;
        const int lr16 = lane & 15;
        short8 af[4], bfr[4];
        #pragma unroll
        for (int mi = 0; mi < 4; ++mi) {
            const int row = wr * 64 + mi * 16 + lr16;
            af[mi] = *(const short8*)(&lA[cur][(row * 4 + (kgl ^ ((row >> 1) & 3))) * 8]);
        }
        #pragma unroll
        for (int ni = 0; ni < 4; ++ni) {
            const int row = wc * 64 + ni * 16 + lr16;
            bfr[ni] = *(const short8*)(&lB[cur][(row * 4 + (kgl ^ ((row >> 1) & 3))) * 8]);
        }

        if (ks < 14) {                      // keep 2 tiles in flight
            int b2 = cur + 2; if (b2 >= 3) b2 -= 3;
            stage(b2, (ks + 2) * 32);
        }

        #pragma unroll
        for (int mi = 0; mi < 4; ++mi)
            #pragma unroll
            for (int ni = 0; ni < 4; ++ni)
                acc[mi][ni] = __builtin_amdgcn_mfma_f32_16x16x32_bf16(
                    af[mi], bfr[ni], acc[mi][ni], 0, 0, 0);

        cur = (cur + 1 == 3) ? 0 : cur + 1;
    }

    // ---- epilogue ---------------------------------------------------------
    const int lr = lane & 15;
    const int lq = lane >> 4;
    #pragma unroll
    for (int ni = 0; ni < 4; ++ni) {
        const int n = n0 + wc * 64 + ni * 16 + lr;
        if (n >= N) continue;
        const float bias = BIAS[n];
        #pragma unroll
        for (int mi = 0; mi < 4; ++mi) {
            #pragma unroll
            for (int r = 0; r < 4; ++r) {
                const int m  = m0 + wr * 64 + mi * 16 + lq * 4 + r;
                const int b  = m >> LOGK;
                const int kd = m & (K_L - 1);
                const float v = acc[mi][ni][r] + bias;
                float* yb = Y + (size_t)b * 370816;
                if constexpr (FUSED) {
                    if constexpr (MODE == 0) {
                        if (n < 27)       yb[kd * 27 + n] = v;
                        else if (n == 27) yb[1728 + kd]   = v;
                        else EXTO[((size_t)(b * 64 + kd)) * 1152 + (n - 28)] = bf16of(v);
                    } else if constexpr (MODE == 1) {
                        if (n < 576) {
                            const float e = bf2f(EXTI[((size_t)(b * 64 + n / 9)) * 1152 + kd * 9 + n % 9]);
                            yb[1792 + kd * 576 + n] = 0.5f * (v + e);
                        } else if (n == 576) yb[75520 + kd] = 0.5f * v;
                        else EXTO[((size_t)(b * 128 + kd)) * 2304 + (n - 577)] = bf16of(v);
                    } else {
                        if (n < 1152) {
                            const float e = bf2f(EXTI[((size_t)(b * 128 + n / 9)) * 2304 + kd * 9 + n % 9]);
                            yb[75648 + kd * 1152 + n] = v + e;
                        } else yb[370560 + kd] = v;
                    }
                } else {
                    if constexpr (MODE == 0) {
                        if (n < 27)       yb[kd * 27 + n] = v;
                        else if (n == 27) yb[1728 + kd]   = v;
                        else {
                            int tt = n - 28, kn = tt / 9, j = tt - kn * 9;
                            yb[1792 + kn * 576 + kd * 9 + j] = 0.5f * v;
                        }
                    } else if constexpr (MODE == 1) {
                        if (n < 576)       yb[1792 + kd * 576 + n] += 0.5f * v;
                        else if (n == 576) yb[75520 + kd] = 0.5f * v;
                        else {
                            int tt = n - 577, kn = tt / 9, j = tt - kn * 9;
                            yb[75648 + kn * 1152 + kd * 9 + j] = v;
                        }
                    } else {
                        if (n < 1152) yb[75648 + kd * 1152 + n] += v;
                        else          yb[370560 + kd] = v;
                    }
                }
            }
        }
    }
}

extern "C" void kernel_launch(void* const* d_in, const int* in_sizes, int n_in,
                              void* d_out, int out_size, void* d_ws, size_t ws_size,
                              hipStream_t stream)
{
    const float* x  = (const float*)d_in[0];
    const float* W0 = (const float*)d_in[1];
    const float* b0 = (const float*)d_in[2];
    const float* W1 = (const float*)d_in[3];
    const float* b1 = (const float*)d_in[4];
    const float* W2 = (const float*)d_in[5];
    const float* b2 = (const float*)d_in[6];
    float* y = (float*)d_out;

    // ws (bf16): XB[128*448*512] | WT0 | WT1 | WT2 | EXT0[128*64*1152] | EXT1[128*128*2304]
    unsigned short* XB   = (unsigned short*)d_ws;
    unsigned short* WT0  = XB   + (size_t)128 * 448 * 512;
    unsigned short* WT1  = WT0  + (size_t)1180 * 512;
    unsigned short* WT2  = WT1  + (size_t)2881 * 512;
    unsigned short* EXT0 = WT2  + (size_t)1153 * 512;
    unsigned short* EXT1 = EXT0 + (size_t)128 * 64 * 1152;
    const size_t NEED_FUSED =
        ((size_t)128 * 448 * 512 + (size_t)5214 * 512 +
         (size_t)128 * 64 * 1152 + (size_t)128 * 128 * 2304) * 2;

    cvt_x<<<dim3(14336), 256, 0, stream>>>(x, XB);
    cvt_w<1180><<<dim3((1180 * 64 + 255) / 256), 256, 0, stream>>>(W0, WT0);
    cvt_w<2881><<<dim3((2881 * 64 + 255) / 256), 256, 0, stream>>>(W1, WT1);
    cvt_w<1153><<<dim3((1153 * 64 + 255) / 256), 256, 0, stream>>>(W2, WT2);

    if (ws_size >= NEED_FUSED) {
        gemm_scatter<0, true><<<dim3(64 * 10),  256, 0, stream>>>(XB, WT0, b0, y, nullptr, EXT0);
        gemm_scatter<1, true><<<dim3(128 * 23), 256, 0, stream>>>(XB, WT1, b1, y, EXT0, EXT1);
        gemm_scatter<2, true><<<dim3(256 * 10), 256, 0, stream>>>(XB, WT2, b2, y, EXT1, nullptr);
    } else {
        gemm_scatter<0, false><<<dim3(64 * 10),  256, 0, stream>>>(XB, WT0, b0, y, nullptr, nullptr);
        gemm_scatter<1, false><<<dim3(128 * 23), 256, 0, stream>>>(XB, WT1, b1, y, nullptr, nullptr);
        gemm_scatter<2, false><<<dim3(256 * 10), 256, 0, stream>>>(XB, WT2, b2, y, nullptr, nullptr);
    }
}